// Round 2
// baseline (1537.292 us; speedup 1.0000x reference)
//
#include <hip/hip_runtime.h>

typedef __attribute__((ext_vector_type(8))) short short8;   // 8 bf16 = 4 VGPRs (MFMA A/B frag)
typedef __attribute__((ext_vector_type(4))) float f32x4;    // MFMA C/D frag
typedef __attribute__((ext_vector_type(4))) float float4v;

#define F 256

__device__ __forceinline__ short f2bf(float f) {
    union { float f; unsigned u; } v; v.f = f;
    unsigned r = (v.u + 0x7fffu + ((v.u >> 16) & 1u)) >> 16;   // RTNE
    return (short)r;
}
__device__ __forceinline__ float bf2f(short s) {
    union { float f; unsigned u; } v; v.u = ((unsigned)(unsigned short)s) << 16;
    return v.f;
}
__device__ __forceinline__ float sigm(float x) {
    return __builtin_amdgcn_rcpf(1.f + __builtin_amdgcn_exp2f(-1.442695041f * x));
}
__device__ __forceinline__ float tanhx(float x) {
    return 1.f - 2.f * __builtin_amdgcn_rcpf(1.f + __builtin_amdgcn_exp2f(2.885390082f * x));
}
__device__ __forceinline__ f32x4 splat4(float v) {
    f32x4 r; r[0] = v; r[1] = v; r[2] = v; r[3] = v; return r;
}

// ---------------------------------------------------------------------------
// Pack kernel (unchanged layout): B-fragment order [ntile][ktile][lane][8].
// B[k][n] = W[n][k]; lane l holds n = nt*16 + (l&15), k = kt*32 + (l>>4)*8 + j.
// ---------------------------------------------------------------------------
__global__ void pack_kernel(const float* __restrict__ Whh, const float* __restrict__ Wih,
                            const float* __restrict__ Wout,
                            short* __restrict__ whh_p, short* __restrict__ wih_hi,
                            short* __restrict__ wih_lo, short* __restrict__ wout_p)
{
    int idx = blockIdx.x * blockDim.x + threadIdx.x;
    if (idx < 64 * 8 * 64) {                       // W_hh + W_ih: 64 n-tiles x 8 k-tiles x 64 lanes
        int lane = idx & 63, kt = (idx >> 6) & 7, nt = idx >> 9;
        int n = nt * 16 + (lane & 15);
        int k = kt * 32 + (lane >> 4) * 8;
        const float* s1 = Whh + n * F + k;
        const float* s2 = Wih + n * F + k;
        #pragma unroll
        for (int j = 0; j < 8; j++) {
            whh_p[idx * 8 + j] = f2bf(s1[j]);
            float v = s2[j];
            short hi = f2bf(v);
            wih_hi[idx * 8 + j] = hi;
            wih_lo[idx * 8 + j] = f2bf(v - bf2f(hi));
        }
    } else {
        int i2 = idx - 64 * 8 * 64;
        if (i2 < 16 * 8 * 64) {                    // W_out: 16 n-tiles
            int lane = i2 & 63, kt = (i2 >> 6) & 7, nt = i2 >> 9;
            int n = nt * 16 + (lane & 15);
            int k = kt * 32 + (lane >> 4) * 8;
            const float* s = Wout + n * F + k;
            #pragma unroll
            for (int j = 0; j < 8; j++) wout_p[i2 * 8 + j] = f2bf(s[j]);
        }
    }
}

// ---------------------------------------------------------------------------
// hbuf holds h (32 rows x 256 cols bf16) in MFMA A-FRAGMENT order:
//   slot[(mt*8 + kt)*64 + lane]*8 + j  <->  h[mt*16 + (lane&15)][kt*32 + (lane>>4)*8 + j]
// so every A-read is a lane-linear ds_read_b128 (zero bank conflicts).
// 16 waves/block; wave w owns cols [16w,16w+16) of each gate (nt = g*16+w).
// ---------------------------------------------------------------------------
__device__ __forceinline__ void gate_mm16(f32x4 (&acc)[4][2], const short* __restrict__ Wp,
                                          const short* hb, int w, int lane)
{
    #pragma unroll
    for (int kt = 0; kt < 8; kt++) {
        short8 a0 = *(const short8*)(hb + (kt * 64 + lane) * 8);
        short8 a1 = *(const short8*)(hb + ((8 + kt) * 64 + lane) * 8);
        #pragma unroll
        for (int g = 0; g < 4; g++) {
            int nt = g * 16 + w;
            short8 b = *(const short8*)(Wp + ((nt * 8 + kt) * 64 + lane) * 8);
            acc[g][0] = __builtin_amdgcn_mfma_f32_16x16x32_bf16(a0, b, acc[g][0], 0, 0, 0);
            acc[g][1] = __builtin_amdgcn_mfma_f32_16x16x32_bf16(a1, b, acc[g][1], 0, 0, 0);
        }
    }
}

__global__ __launch_bounds__(1024)
void lstm_fused(const float* __restrict__ x, const float* __restrict__ b_ih,
                const float* __restrict__ b_hh, const float* __restrict__ c0,
                const float* __restrict__ b_out,
                const short* __restrict__ whh_p, const short* __restrict__ wih_hi,
                const short* __restrict__ wih_lo, const short* __restrict__ wout_p,
                const int* __restrict__ seqlen, float* __restrict__ out)
{
    __shared__ short hbuf[2 * 8 * 64 * 8];    // 16 KB, A-frag order
    const int T    = *seqlen;
    const int tid  = threadIdx.x;
    const int lane = tid & 63;
    const int w    = tid >> 6;        // wave 0..15
    const int l15  = lane & 15;
    const int quad = lane >> 4;
    const int row0 = blockIdx.x * 32;

    // ---- load this block's 32 x-rows (fp32, nontemporal dwordx4) ----
    const int xr = tid >> 5;          // 0..31
    const int xc = (tid & 31) * 8;    // 0..248
    float xv[8];
    {
        const float4v* xp = (const float4v*)(x + (size_t)(row0 + xr) * F + xc);
        float4v v0 = __builtin_nontemporal_load(xp);
        float4v v1 = __builtin_nontemporal_load(xp + 1);
        #pragma unroll
        for (int j = 0; j < 4; j++) { xv[j] = v0[j]; xv[4 + j] = v1[j]; }
    }
    // x-staging address in A-frag layout (8 consecutive shorts -> one b128 write)
    short* xst = hbuf + (size_t)(xr >> 4) * 4096 + ((tid & 31) >> 2) * 512
                      + ((tid & 31) & 3) * 128 + (xr & 15) * 8;

    // ---- x_proj = x @ W_ih^T + biases, fp32-accurate via 3-term split bf16 ----
    f32x4 xpj[4][2];
    #pragma unroll
    for (int g = 0; g < 4; g++) { xpj[g][0] = splat4(0.f); xpj[g][1] = splat4(0.f); }

    {   // stage x_lo, accumulate lo x Wih_hi
        short8 s;
        #pragma unroll
        for (int j = 0; j < 8; j++) { short hi = f2bf(xv[j]); s[j] = f2bf(xv[j] - bf2f(hi)); }
        *(short8*)xst = s;
    }
    __syncthreads();
    gate_mm16(xpj, wih_hi, hbuf, w, lane);
    __syncthreads();
    {   // stage x_hi (stays as h_0), accumulate hi x Wih_hi + hi x Wih_lo
        short8 s;
        #pragma unroll
        for (int j = 0; j < 8; j++) s[j] = f2bf(xv[j]);
        *(short8*)xst = s;
    }
    __syncthreads();
    gate_mm16(xpj, wih_hi, hbuf, w, lane);
    gate_mm16(xpj, wih_lo, hbuf, w, lane);

    // biases: gate-col n = 256g + 16w + l15
    #pragma unroll
    for (int g = 0; g < 4; g++) {
        int n = g * 256 + w * 16 + l15;
        float bias = b_ih[n] + b_hh[n];
        #pragma unroll
        for (int mt = 0; mt < 2; mt++)
            #pragma unroll
            for (int r = 0; r < 4; r++) xpj[g][mt][r] += bias;
    }

    // cell state init + output bias (wave's h-col = 16w + l15)
    const int hcol = w * 16 + l15;
    float cst[2][4];
    const float cv = c0[hcol];
    const float bo = b_out[hcol];
    #pragma unroll
    for (int mt = 0; mt < 2; mt++)
        #pragma unroll
        for (int r = 0; r < 4; r++) cst[mt][r] = cv;

    // h-write offset in A-frag layout for this lane's column
    const int hoff = (hcol >> 5) * 512 + ((hcol >> 3) & 3) * 128 + (hcol & 7) + quad * 32;

    const size_t orow = (size_t)T * F;
    float* obase = out + (size_t)row0 * orow + hcol;   // + row*orow + t*F

    for (int t = 0; t < T; t++) {
        // gates = x_proj + h_t @ W_hh^T
        f32x4 acc[4][2];
        #pragma unroll
        for (int g = 0; g < 4; g++) { acc[g][0] = xpj[g][0]; acc[g][1] = xpj[g][1]; }
        gate_mm16(acc, whh_p, hbuf, w, lane);

        __syncthreads();   // all waves done reading h_t

        // in-register LSTM cell update (fp32), write h_{t+1} in A-frag order
        #pragma unroll
        for (int mt = 0; mt < 2; mt++)
            #pragma unroll
            for (int r = 0; r < 4; r++) {
                float ig = sigm(acc[0][mt][r]);
                float fg = sigm(acc[1][mt][r]);
                float gg = tanhx(acc[2][mt][r]);
                float og = sigm(acc[3][mt][r]);
                float c  = fg * cst[mt][r] + ig * gg;
                cst[mt][r] = c;
                hbuf[mt * 4096 + hoff + r * 8] = f2bf(og * tanhx(c));
            }
        __syncthreads();   // h_{t+1} visible

        // fused output projection: out[., t, .] = h_{t+1} @ W_out^T + b_out
        f32x4 oacc[2];
        oacc[0] = splat4(bo); oacc[1] = splat4(bo);
        #pragma unroll
        for (int kt = 0; kt < 8; kt++) {
            short8 a0 = *(const short8*)(hbuf + (kt * 64 + lane) * 8);
            short8 a1 = *(const short8*)(hbuf + ((8 + kt) * 64 + lane) * 8);
            short8 b  = *(const short8*)(wout_p + ((w * 8 + kt) * 64 + lane) * 8);
            oacc[0] = __builtin_amdgcn_mfma_f32_16x16x32_bf16(a0, b, oacc[0], 0, 0, 0);
            oacc[1] = __builtin_amdgcn_mfma_f32_16x16x32_bf16(a1, b, oacc[1], 0, 0, 0);
        }
        // nontemporal stores: keep the streaming output out of L2
        float* op = obase + (size_t)t * F;
        #pragma unroll
        for (int mt = 0; mt < 2; mt++)
            #pragma unroll
            for (int r = 0; r < 4; r++)
                __builtin_nontemporal_store(oacc[mt][r],
                    op + (size_t)(mt * 16 + quad * 4 + r) * orow);
    }
}

extern "C" void kernel_launch(void* const* d_in, const int* in_sizes, int n_in,
                              void* d_out, int out_size, void* d_ws, size_t ws_size,
                              hipStream_t stream)
{
    const float* x    = (const float*)d_in[0];
    const float* Wih  = (const float*)d_in[1];
    const float* Whh  = (const float*)d_in[2];
    const float* bih  = (const float*)d_in[3];
    const float* bhh  = (const float*)d_in[4];
    const float* c0   = (const float*)d_in[5];
    const float* Wout = (const float*)d_in[6];
    const float* bout = (const float*)d_in[7];
    const int* seqlen = (const int*)d_in[8];

    short* whh_p  = (short*)d_ws;            // 1024*256 bf16 = 512 KB
    short* wih_hi = whh_p  + 1024 * 256;     // 512 KB
    short* wih_lo = wih_hi + 1024 * 256;     // 512 KB
    short* wout_p = wih_lo + 1024 * 256;     // 128 KB
    (void)ws_size; (void)in_sizes; (void)n_in; (void)out_size;

    pack_kernel<<<160, 256, 0, stream>>>(Whh, Wih, Wout, whh_p, wih_hi, wih_lo, wout_p);
    lstm_fused<<<128, 1024, 0, stream>>>(x, bih, bhh, c0, bout,
                                         whh_p, wih_hi, wih_lo, wout_p,
                                         seqlen, (float*)d_out);
}

// Round 3
// 1439.330 us; speedup vs baseline: 1.0681x; 1.0681x over previous
//
#include <hip/hip_runtime.h>

typedef __attribute__((ext_vector_type(8))) short short8;   // 8 bf16 = 4 VGPRs (MFMA A/B frag)
typedef __attribute__((ext_vector_type(4))) float f32x4;    // MFMA C/D frag
typedef __attribute__((ext_vector_type(4))) float float4v;

#define F 256

__device__ __forceinline__ short f2bf(float f) {
    union { float f; unsigned u; } v; v.f = f;
    unsigned r = (v.u + 0x7fffu + ((v.u >> 16) & 1u)) >> 16;   // RTNE
    return (short)r;
}
__device__ __forceinline__ float bf2f(short s) {
    union { float f; unsigned u; } v; v.u = ((unsigned)(unsigned short)s) << 16;
    return v.f;
}
__device__ __forceinline__ float sigm(float x) {
    return __builtin_amdgcn_rcpf(1.f + __builtin_amdgcn_exp2f(-1.442695041f * x));
}
__device__ __forceinline__ float tanhx(float x) {
    return 1.f - 2.f * __builtin_amdgcn_rcpf(1.f + __builtin_amdgcn_exp2f(2.885390082f * x));
}
__device__ __forceinline__ f32x4 splat4(float v) {
    f32x4 r; r[0] = v; r[1] = v; r[2] = v; r[3] = v; return r;
}

// ---------------------------------------------------------------------------
// Pack kernel: fragment order [tile][ktile][lane][8].  Stored value at
// lane l, tile nt, chunk kt:  W[nt*16 + (l&15)][kt*32 + (l>>4)*8 + j].
// Read as B-frag: B[k][n] = W[n][k] (weights for gates, n = gate col).
// Read as A-frag: A[m][k] = W[m][k] (W_out for the swapped output proj).
// ---------------------------------------------------------------------------
__global__ void pack_kernel(const float* __restrict__ Whh, const float* __restrict__ Wih,
                            const float* __restrict__ Wout,
                            short* __restrict__ whh_p, short* __restrict__ wih_hi,
                            short* __restrict__ wih_lo, short* __restrict__ wout_p)
{
    int idx = blockIdx.x * blockDim.x + threadIdx.x;
    if (idx < 64 * 8 * 64) {                       // W_hh + W_ih: 64 n-tiles x 8 k-tiles x 64 lanes
        int lane = idx & 63, kt = (idx >> 6) & 7, nt = idx >> 9;
        int n = nt * 16 + (lane & 15);
        int k = kt * 32 + (lane >> 4) * 8;
        const float* s1 = Whh + n * F + k;
        const float* s2 = Wih + n * F + k;
        #pragma unroll
        for (int j = 0; j < 8; j++) {
            whh_p[idx * 8 + j] = f2bf(s1[j]);
            float v = s2[j];
            short hi = f2bf(v);
            wih_hi[idx * 8 + j] = hi;
            wih_lo[idx * 8 + j] = f2bf(v - bf2f(hi));
        }
    } else {
        int i2 = idx - 64 * 8 * 64;
        if (i2 < 16 * 8 * 64) {                    // W_out: 16 tiles
            int lane = i2 & 63, kt = (i2 >> 6) & 7, nt = i2 >> 9;
            int n = nt * 16 + (lane & 15);
            int k = kt * 32 + (lane >> 4) * 8;
            const float* s = Wout + n * F + k;
            #pragma unroll
            for (int j = 0; j < 8; j++) wout_p[i2 * 8 + j] = f2bf(s[j]);
        }
    }
}

// ---------------------------------------------------------------------------
// hbuf holds h (32 rows x 256 cols bf16) in MFMA A/B-FRAGMENT order:
//   slot[(mt*8 + kt)*64 + lane]*8 + j  <->  h[mt*16 + (lane&15)][kt*32 + (lane>>4)*8 + j]
// Every read is a lane-linear ds_read_b128 (conflict-free); the same reads
// serve as A-frags (h rows = M) for gates and as B-frags (h rows = N) for the
// swapped output projection.
// 16 waves/block; wave w owns gate cols nt = g*16 + w.
// ---------------------------------------------------------------------------
__device__ __forceinline__ void gate_mm16(f32x4 (&acc)[4][2], const short* __restrict__ Wp,
                                          const short* hb, int w, int lane)
{
    #pragma unroll
    for (int kt = 0; kt < 8; kt++) {
        short8 a0 = *(const short8*)(hb + (kt * 64 + lane) * 8);
        short8 a1 = *(const short8*)(hb + ((8 + kt) * 64 + lane) * 8);
        #pragma unroll
        for (int g = 0; g < 4; g++) {
            int nt = g * 16 + w;
            short8 b = *(const short8*)(Wp + ((nt * 8 + kt) * 64 + lane) * 8);
            acc[g][0] = __builtin_amdgcn_mfma_f32_16x16x32_bf16(a0, b, acc[g][0], 0, 0, 0);
            acc[g][1] = __builtin_amdgcn_mfma_f32_16x16x32_bf16(a1, b, acc[g][1], 0, 0, 0);
        }
    }
}

__global__ __launch_bounds__(1024)
void lstm_fused(const float* __restrict__ x, const float* __restrict__ b_ih,
                const float* __restrict__ b_hh, const float* __restrict__ c0,
                const float* __restrict__ b_out,
                const short* __restrict__ whh_p, const short* __restrict__ wih_hi,
                const short* __restrict__ wih_lo, const short* __restrict__ wout_p,
                const int* __restrict__ seqlen, float* __restrict__ out)
{
    __shared__ short hbuf[2 * 8 * 64 * 8];    // 16 KB, A/B-frag order
    const int T    = *seqlen;
    const int tid  = threadIdx.x;
    const int lane = tid & 63;
    const int w    = tid >> 6;        // wave 0..15
    const int l15  = lane & 15;
    const int quad = lane >> 4;
    const int row0 = blockIdx.x * 32;

    // ---- load this block's 32 x-rows (fp32, plain coalesced dwordx4) ----
    const int xr = tid >> 5;          // 0..31
    const int xc = (tid & 31) * 8;    // 0..248
    float xv[8];
    {
        const float4v* xp = (const float4v*)(x + (size_t)(row0 + xr) * F + xc);
        float4v v0 = xp[0];
        float4v v1 = xp[1];
        #pragma unroll
        for (int j = 0; j < 4; j++) { xv[j] = v0[j]; xv[4 + j] = v1[j]; }
    }
    // x-staging address in A-frag layout (8 consecutive shorts -> one b128 write)
    short* xst = hbuf + (size_t)(xr >> 4) * 4096 + ((tid & 31) >> 2) * 512
                      + ((tid & 31) & 3) * 128 + (xr & 15) * 8;

    // ---- x_proj = x @ W_ih^T + biases, fp32-accurate via 3-term split bf16 ----
    f32x4 xpj[4][2];
    #pragma unroll
    for (int g = 0; g < 4; g++) { xpj[g][0] = splat4(0.f); xpj[g][1] = splat4(0.f); }

    {   // stage x_lo, accumulate lo x Wih_hi
        short8 s;
        #pragma unroll
        for (int j = 0; j < 8; j++) { short hi = f2bf(xv[j]); s[j] = f2bf(xv[j] - bf2f(hi)); }
        *(short8*)xst = s;
    }
    __syncthreads();
    gate_mm16(xpj, wih_hi, hbuf, w, lane);
    __syncthreads();
    {   // stage x_hi (stays as h_0), accumulate hi x Wih_hi + hi x Wih_lo
        short8 s;
        #pragma unroll
        for (int j = 0; j < 8; j++) s[j] = f2bf(xv[j]);
        *(short8*)xst = s;
    }
    __syncthreads();
    gate_mm16(xpj, wih_hi, hbuf, w, lane);
    gate_mm16(xpj, wih_lo, hbuf, w, lane);

    // biases: gate-col n = 256g + 16w + l15
    #pragma unroll
    for (int g = 0; g < 4; g++) {
        int n = g * 256 + w * 16 + l15;
        float bias = b_ih[n] + b_hh[n];
        #pragma unroll
        for (int mt = 0; mt < 2; mt++)
            #pragma unroll
            for (int r = 0; r < 4; r++) xpj[g][mt][r] += bias;
    }

    // cell state init (wave's gate/h col = 16w + l15)
    const int hcol = w * 16 + l15;
    float cst[2][4];
    const float cv = c0[hcol];
    #pragma unroll
    for (int mt = 0; mt < 2; mt++)
        #pragma unroll
        for (int r = 0; r < 4; r++) cst[mt][r] = cv;

    // output bias for the SWAPPED projection: this lane produces out cols 16w+4q+r
    float bor[4];
    #pragma unroll
    for (int r = 0; r < 4; r++) bor[r] = b_out[w * 16 + quad * 4 + r];

    // h-write offset in A-frag layout for this lane's column
    const int hoff = (hcol >> 5) * 512 + ((hcol >> 3) & 3) * 128 + (hcol & 7) + quad * 32;

    const size_t orow = (size_t)T * F;
    // swapped-proj store base: row = row0 + mt*16 + l15, col = 16w + 4*quad + r
    float* obase = out + (size_t)(row0 + l15) * orow + w * 16 + quad * 4;

    for (int t = 0; t < T; t++) {
        // gates = x_proj + h_t @ W_hh^T
        f32x4 acc[4][2];
        #pragma unroll
        for (int g = 0; g < 4; g++) { acc[g][0] = xpj[g][0]; acc[g][1] = xpj[g][1]; }
        gate_mm16(acc, whh_p, hbuf, w, lane);

        __syncthreads();   // all waves done reading h_t

        // in-register LSTM cell update (fp32), write h_{t+1} in A-frag order
        #pragma unroll
        for (int mt = 0; mt < 2; mt++)
            #pragma unroll
            for (int r = 0; r < 4; r++) {
                float ig = sigm(acc[0][mt][r]);
                float fg = sigm(acc[1][mt][r]);
                float gg = tanhx(acc[2][mt][r]);
                float og = sigm(acc[3][mt][r]);
                float c  = fg * cst[mt][r] + ig * gg;
                cst[mt][r] = c;
                hbuf[mt * 4096 + hoff + r * 8] = f2bf(og * tanhx(c));
            }
        __syncthreads();   // h_{t+1} visible

        // fused output projection, operand-swapped:
        //   D = W_out(A-frag, tile w) x h^T(B-frag)  ->  lane holds 4 consecutive
        //   out cols (16w+4q..+3) for batch row l15 -> one dwordx4 NT store per m-tile.
        f32x4 oacc[2];
        #pragma unroll
        for (int mt = 0; mt < 2; mt++)
            #pragma unroll
            for (int r = 0; r < 4; r++) oacc[mt][r] = bor[r];
        #pragma unroll
        for (int kt = 0; kt < 8; kt++) {
            short8 b0 = *(const short8*)(hbuf + (kt * 64 + lane) * 8);
            short8 b1 = *(const short8*)(hbuf + ((8 + kt) * 64 + lane) * 8);
            short8 aw = *(const short8*)(wout_p + ((w * 8 + kt) * 64 + lane) * 8);
            oacc[0] = __builtin_amdgcn_mfma_f32_16x16x32_bf16(aw, b0, oacc[0], 0, 0, 0);
            oacc[1] = __builtin_amdgcn_mfma_f32_16x16x32_bf16(aw, b1, oacc[1], 0, 0, 0);
        }
        // full 16B/lane NT stores, 64B-aligned segments per row: no L2 allocate, no RMW
        float* op = obase + (size_t)t * F;
        __builtin_nontemporal_store(oacc[0], (float4v*)op);
        __builtin_nontemporal_store(oacc[1], (float4v*)(op + 16 * orow));
    }
}

extern "C" void kernel_launch(void* const* d_in, const int* in_sizes, int n_in,
                              void* d_out, int out_size, void* d_ws, size_t ws_size,
                              hipStream_t stream)
{
    const float* x    = (const float*)d_in[0];
    const float* Wih  = (const float*)d_in[1];
    const float* Whh  = (const float*)d_in[2];
    const float* bih  = (const float*)d_in[3];
    const float* bhh  = (const float*)d_in[4];
    const float* c0   = (const float*)d_in[5];
    const float* Wout = (const float*)d_in[6];
    const float* bout = (const float*)d_in[7];
    const int* seqlen = (const int*)d_in[8];

    short* whh_p  = (short*)d_ws;            // 1024*256 bf16 = 512 KB
    short* wih_hi = whh_p  + 1024 * 256;     // 512 KB
    short* wih_lo = wih_hi + 1024 * 256;     // 512 KB
    short* wout_p = wih_lo + 1024 * 256;     // 128 KB
    (void)ws_size; (void)in_sizes; (void)n_in; (void)out_size;

    pack_kernel<<<160, 256, 0, stream>>>(Whh, Wih, Wout, whh_p, wih_hi, wih_lo, wout_p);
    lstm_fused<<<128, 1024, 0, stream>>>(x, bih, bhh, c0, bout,
                                         whh_p, wih_hi, wih_lo, wout_p,
                                         seqlen, (float*)d_out);
}